// Round 10
// baseline (467.808 us; speedup 1.0000x reference)
//
#include <hip/hip_runtime.h>
#include <math.h>

#define TSTEPS 512
#define RPB 8
#define L2E  1.4426950408889634f
#define L2E2 2.8853900817779268f   // 2*log2(e)

typedef __attribute__((ext_vector_type(4))) short short4v;
typedef __attribute__((ext_vector_type(8))) short short8;
typedef __attribute__((ext_vector_type(4))) float f32x4;
typedef __bf16 bf16x8 __attribute__((ext_vector_type(8)));

__device__ __forceinline__ short f2bf(float f) {            // RNE float->bf16
    union { float f; unsigned u; } v; v.f = f;
    return (short)((v.u + 0x7FFFu + ((v.u >> 16) & 1u)) >> 16);
}
__device__ __forceinline__ unsigned pkbf(float lo, float hi) {  // HW RNE pack
    unsigned r;
    asm("v_cvt_pk_bf16_f32 %0, %1, %2" : "=v"(r) : "v"(lo), "v"(hi));
    return r;
}
__device__ __forceinline__ float rcp_f(float x) { return __builtin_amdgcn_rcpf(x); }
__device__ __forceinline__ float ex2(float x)   { return __builtin_amdgcn_exp2f(x); }
__device__ __forceinline__ f32x4 mfma16(bf16x8 a, bf16x8 b, f32x4 c) {
    return __builtin_amdgcn_mfma_f32_16x16x32_bf16(a, b, c, 0, 0, 0);
}

// 256 blocks x 512 threads (8 waves, 2/SIMD). Merged 16x16 MFMA tile,
// K=224 block-diagonal, LAG-2 pipeline (see r8) — UNCHANGED math.
// THIS ROUND: GATE-SPLIT WAVE SPECIALIZATION. rocprof closes exactly as
// wall = MFMA-busy + VALU-busy + stall with 1 wave/SIMD (MFMA blocks its
// wave; pipes strictly additive). m114: two waves on one CU feeding the
// matrix and VALU pipes DO overlap (time=max). So: waves 0-3 ("IG") own
// gate-accs g,i for cells 16s..16s+15; waves 4-7 ("FO") own f,o for the
// same cells. 14 MFMAs/wave (CU total unchanged). Per step:
//   phase 1 (both roles): ds_read frags, 14 MFMAs, role trans work
//     IG: ig = sig(i)*tanh(g) (shared rcp), 4 f32 -> IG LDS buffer
//     FO: fv = sig(f), do = 1+e^-o
//   [mid barrier]
//   phase 2: FO reads ig, c-update + h (shared rcp), h-store; IG stages x
//   [end barrier]
// ig transfers as exact f32 -> arithmetic value-identical to the r9
// kernel (absmax unchanged). c-state + freeze live in FO waves.
#define STEPB(SUB, PREF, XST, FRZ, XNXT, XP, XS, YP, YS) do {           \
    const short* haS_ = ((SUB) & 1) ? haB : haA;                        \
    const short* hcS_ = ((SUB) & 1) ? hcB : hcA;                        \
    const bf16x8 a1 = *(const bf16x8*)(haS_ + oH1);                     \
    const bf16x8 a2 = *(const bf16x8*)(haS_ + oH1 + 32);                \
    const bf16x8 a5 = *(const bf16x8*)(hcS_ + oH2);                     \
    const bf16x8 a6 = *(const bf16x8*)(hcS_ + oH2 + 32);                \
    const bf16x8 a3 = *(const bf16x8*)(haS_ + oH2);                     \
    const bf16x8 a4 = *(const bf16x8*)(haS_ + oH2 + 32);                \
    const bf16x8 a0n = *(const bf16x8*)(XNXT);                          \
    if ((PREF) && !roleB) {                                             \
        xr0 = *(const float4*)(xp);                                     \
        xr1 = *(const float4*)(xp + 16);                                \
    }                                                                   \
    /* next-acc chunk 0 (bias C-in) + cur-acc chunks 1,2,5,6 + next 3,4 */ \
    YP = mfma16(a0n, BP_0, BPc); YS = mfma16(a0n, BS_0, BSc);           \
    XP = mfma16(a1, BP_1, XP);  XS = mfma16(a1, BS_1, XS);              \
    XP = mfma16(a2, BP_2, XP);  XS = mfma16(a2, BS_2, XS);              \
    XP = mfma16(a5, BP_5, XP);  XS = mfma16(a5, BS_5, XS);              \
    XP = mfma16(a6, BP_6, XP);  XS = mfma16(a6, BS_6, XS);              \
    YP = mfma16(a3, BP_3, YP);  YS = mfma16(a3, BS_3, YS);              \
    YP = mfma16(a4, BP_4, YP);  YS = mfma16(a4, BS_4, YS);              \
    float fv0, fv1, fv2, fv3, do0, do1, do2, do3;                       \
    if (!roleB) {            /* XP = G preacts, XS = I preacts */       \
        {   const float eg = ex2(XP[0]), ei = ex2(-XS[0]);              \
            igW[0]   = (eg - 1.0f) * rcp_f((1.0f + ei) * (1.0f + eg)); } \
        {   const float eg = ex2(XP[1]), ei = ex2(-XS[1]);              \
            igW[256] = (eg - 1.0f) * rcp_f((1.0f + ei) * (1.0f + eg)); } \
        {   const float eg = ex2(XP[2]), ei = ex2(-XS[2]);              \
            igW[512] = (eg - 1.0f) * rcp_f((1.0f + ei) * (1.0f + eg)); } \
        {   const float eg = ex2(XP[3]), ei = ex2(-XS[3]);              \
            igW[768] = (eg - 1.0f) * rcp_f((1.0f + ei) * (1.0f + eg)); } \
    } else {                 /* XP = F preacts, XS = O preacts */       \
        fv0 = rcp_f(1.0f + ex2(-XP[0])); do0 = 1.0f + ex2(-XS[0]);      \
        fv1 = rcp_f(1.0f + ex2(-XP[1])); do1 = 1.0f + ex2(-XS[1]);      \
        fv2 = rcp_f(1.0f + ex2(-XP[2])); do2 = 1.0f + ex2(-XS[2]);      \
        fv3 = rcp_f(1.0f + ex2(-XP[3])); do3 = 1.0f + ex2(-XS[3]);      \
    }                                                                   \
    asm volatile("s_waitcnt lgkmcnt(0)" ::: "memory");                  \
    __builtin_amdgcn_s_barrier();        /* mid: ig published */        \
    if (roleB) {                                                        \
        const float ig0 = igR[0],   ig1 = igR[256];                     \
        const float ig2 = igR[512], ig3 = igR[768];                     \
        short* hd_ = (((SUB) & 1) == 0) ? hw1 : hw0;                    \
        float hv0, hv1, hv2, hv3;                                       \
        {   const float cn = fmaf(fv0, c0, ig0); c0 = (FRZ) ? 0.0f : cn; \
            const float ec = ex2(c0 * L2E2);                            \
            hv0 = (ec - 1.0f) * rcp_f(do0 * (1.0f + ec)); }             \
        {   const float cn = fmaf(fv1, c1, ig1); c1 = (FRZ) ? 0.0f : cn; \
            const float ec = ex2(c1 * L2E2);                            \
            hv1 = (ec - 1.0f) * rcp_f(do1 * (1.0f + ec)); }             \
        {   const float cn = fmaf(fv2, c2, ig2); c2 = (FRZ) ? 0.0f : cn; \
            const float ec = ex2(c2 * L2E2);                            \
            hv2 = (ec - 1.0f) * rcp_f(do2 * (1.0f + ec)); }             \
        {   const float cn = fmaf(fv3, c3, ig3); c3 = (FRZ) ? 0.0f : cn; \
            const float ec = ex2(c3 * L2E2);                            \
            hv3 = (ec - 1.0f) * rcp_f(do3 * (1.0f + ec)); }             \
        const unsigned pA_ = pkbf(hv0, hv1);                            \
        const unsigned pB_ = pkbf(hv2, hv3);                            \
        hd_[0]   = (short)pA_; hd_[72]  = (short)(pA_ >> 16);           \
        hd_[144] = (short)pB_; hd_[216] = (short)(pB_ >> 16);           \
    } else if (XST) {                                                   \
        short4v pa_; pa_[0] = f2bf(xr0.x); pa_[1] = f2bf(xr0.y);        \
        pa_[2] = f2bf(xr0.z); pa_[3] = f2bf(xr0.w);                     \
        *(short4v*)(xsW) = pa_;                                         \
        short4v pb_; pb_[0] = f2bf(xr1.x); pb_[1] = f2bf(xr1.y);        \
        pb_[2] = f2bf(xr1.z); pb_[3] = f2bf(xr1.w);                     \
        *(short4v*)(xsW + 16) = pb_;                                    \
    }                                                                   \
    asm volatile("s_waitcnt lgkmcnt(0)" ::: "memory");                  \
    __builtin_amdgcn_s_barrier();        /* end: h published */         \
} while (0)

__global__ __launch_bounds__(512)
void lstm_mfma_68547678044465(const float* __restrict__ x,
                              const float* __restrict__ Wih0, const float* __restrict__ Whh0,
                              const float* __restrict__ bih0, const float* __restrict__ bhh0,
                              const float* __restrict__ Wih1, const float* __restrict__ Whh1,
                              const float* __restrict__ bih1, const float* __restrict__ bhh1,
                              const float* __restrict__ ln_g, const float* __restrict__ ln_b,
                              const float* __restrict__ fcw, const float* __restrict__ fcb,
                              float* __restrict__ out)
{
    __shared__ __align__(16) short XB[2][8][16][40];  // x bf16; rows 8-15 always zero
    __shared__ __align__(16) short HA[2][24][72];     // rows 0-7 zero | 8-15 h0 | 16-23 zero
    __shared__ __align__(16) short HC[2][16][72];     // rows 0-7 zero | 8-15 h1
    __shared__ __align__(16) float HF[8][64];         // final h1 fp32 for LN
    __shared__ __align__(16) float IG[4][4][64];      // ig exchange [r][cellgrp][lane]

    const int tid  = threadIdx.x;
    const int wl   = tid >> 6;           // wave 0..7
    const bool roleB = (wl >= 4);        // waves 4-7: f,o + c/h ("FO")
    const int s    = wl & 3;             // cell group 0..3
    const int lane = tid & 63;
    const int n    = lane & 15;          // A row m / C col n
    const int q    = lane >> 4;          // k-quad / C row group
    const int rb   = blockIdx.x * RPB;
    const int cell = s * 16 + n;         // h-dim cell 0..63
    const bool qhi = (q >= 2);

    // ---- role gate rows: IG -> (g, i); FO -> (f, o) ----
    const int   gP  = roleB ? (64 + cell)  : (128 + cell);   // f : g
    const int   gS  = roleB ? (192 + cell) : cell;           // o : i
    const float scP = roleB ? L2E : L2E2;

    // ---- B-fragments: 2 gate-tiles x 7 K-chunks per wave ----
    auto loadB = [&](const float* wrow, float sc) -> bf16x8 {
        const float4 lo = *(const float4*)(wrow);
        const float4 hi = *(const float4*)(wrow + 4);
        short8 r;
        r[0] = f2bf(lo.x * sc); r[1] = f2bf(lo.y * sc);
        r[2] = f2bf(lo.z * sc); r[3] = f2bf(lo.w * sc);
        r[4] = f2bf(hi.x * sc); r[5] = f2bf(hi.y * sc);
        r[6] = f2bf(hi.z * sc); r[7] = f2bf(hi.w * sc);
        return (bf16x8)r;
    };
    const int ko = q * 8;
    const bf16x8 BP_0 = loadB(Wih0 + gP * 32 + ko, scP);
    const bf16x8 BP_1 = loadB(Whh0 + gP * 64 + ko, scP);
    const bf16x8 BP_2 = loadB(Whh0 + gP * 64 + 32 + ko, scP);
    const bf16x8 BP_3 = loadB(Wih1 + gP * 64 + ko, scP);
    const bf16x8 BP_4 = loadB(Wih1 + gP * 64 + 32 + ko, scP);
    const bf16x8 BP_5 = loadB(Whh1 + gP * 64 + ko, scP);
    const bf16x8 BP_6 = loadB(Whh1 + gP * 64 + 32 + ko, scP);
    const bf16x8 BS_0 = loadB(Wih0 + gS * 32 + ko, L2E);
    const bf16x8 BS_1 = loadB(Whh0 + gS * 64 + ko, L2E);
    const bf16x8 BS_2 = loadB(Whh0 + gS * 64 + 32 + ko, L2E);
    const bf16x8 BS_3 = loadB(Wih1 + gS * 64 + ko, L2E);
    const bf16x8 BS_4 = loadB(Wih1 + gS * 64 + 32 + ko, L2E);
    const bf16x8 BS_5 = loadB(Whh1 + gS * 64 + ko, L2E);
    const bf16x8 BS_6 = loadB(Whh1 + gS * 64 + 32 + ko, L2E);

    // ---- biases (per-lane layer select) ----
    float bP, bS;
    if (!qhi) { bP = (bih0[gP] + bhh0[gP]) * scP; bS = (bih0[gS] + bhh0[gS]) * L2E; }
    else      { bP = (bih1[gP] + bhh1[gP]) * scP; bS = (bih1[gS] + bhh1[gS]) * L2E; }
    const f32x4 BPc = {bP, bP, bP, bP}, BSc = {bS, bS, bS, bS};

    // ---- zero LDS (zero rows must stay zero; parity bufs start 0) ----
    { int* z = (int*)XB; for (int i = tid; i < 5120; i += 512) z[i] = 0; }
    { int* z = (int*)HA; for (int i = tid; i < 1728; i += 512) z[i] = 0; }
    { int* z = (int*)HC; for (int i = tid; i < 1152; i += 512) z[i] = 0; }

    // ---- per-lane invariant LDS pointers / offsets ----
    const short* haA = &HA[0][0][0];
    const short* haB = &HA[1][0][0];
    const short* hcA = &HC[0][0][0];
    const short* hcB = &HC[1][0][0];
    const int oH1 = (8 + n) * 72 + q * 8;     // h0 rows 8+m (L0 side)
    const int oH2 = n * 72 + q * 8;           // rows m (zero pad | data)
    const short* xb0 = &XB[0][0][0][0] + (n * 40 + q * 8);
    const short* xb1 = xb0 + 5120;
    short* hw0 = (qhi ? &HC[0][8 + (q & 1) * 4][0]
                      : &HA[0][8 + (q & 1) * 4][0]) + cell;   // FO writes, parity-0
    short* hw1 = (qhi ? &HC[1][8 + (q & 1) * 4][0]
                      : &HA[1][8 + (q & 1) * 4][0]) + cell;   // parity-1
    float* igW = &IG[0][s][lane];             // IG writes r at igW[r*256]
    const float* igR = igW;                    // FO reads (same mapping)

    // ---- x staging (IG waves only; tid<256 -> identical mapping) ----
    const int ss = (tid >> 5) & 7, sm = (tid >> 2) & 7, kq = tid & 3;
    const float* xrow = x + (size_t)(rb + sm) * (TSTEPS * 32);
    short* xs0 = &XB[0][ss][sm][0] + kq * 4;
    short* xs1 = xs0 + 5120;
    const float* xp = xrow + (8 + ss) * 32 + kq * 4;   // group-1 prefetch base
    float4 xr0, xr1;
    if (!roleB) {
        xr0 = *(const float4*)(xrow + ss * 32 + kq * 4);
        xr1 = *(const float4*)(xrow + ss * 32 + kq * 4 + 16);
        short4v pa; pa[0] = f2bf(xr0.x); pa[1] = f2bf(xr0.y);
        pa[2] = f2bf(xr0.z); pa[3] = f2bf(xr0.w);
        *(short4v*)(xs0) = pa;
        short4v pb; pb[0] = f2bf(xr1.x); pb[1] = f2bf(xr1.y);
        pb[2] = f2bf(xr1.z); pb[3] = f2bf(xr1.w);
        *(short4v*)(xs0 + 16) = pb;
    }
    __syncthreads();

    float c0 = 0.0f, c1 = 0.0f, c2 = 0.0f, c3 = 0.0f;   // live in FO waves

    // ---- prologue: cur-accs for j=0 = bias + x_0 chunk 0 ----
    f32x4 P1, S1, P2 = {0, 0, 0, 0}, S2 = {0, 0, 0, 0};
    {
        const bf16x8 a0p = *(const bf16x8*)(xb0);      // x_0 frag
        P1 = mfma16(a0p, BP_0, BPc); S1 = mfma16(a0p, BS_0, BSc);
    }

#pragma unroll 1
    for (int g = 0; g < 64; ++g) {
        const short* xbR = (g & 1) ? xb1 : xb0;   // read buf = g&1
        const short* xbO = (g & 1) ? xb0 : xb1;   // other buf (next group)
        short* xsW       = (g & 1) ? xs0 : xs1;   // stage target = (g+1)&1
        const bool fz = (g == 0) && qhi;          // phantom L1 steps -2,-1
        const bool pg = (g < 63);
        STEPB(0, pg, 0, fz,    xbR + 640,  P1, S1, P2, S2);
        STEPB(1, 0, 0, fz,     xbR + 1280, P2, S2, P1, S1);
        STEPB(2, 0, 0, false,  xbR + 1920, P1, S1, P2, S2);
        STEPB(3, 0, 0, false,  xbR + 2560, P2, S2, P1, S1);
        STEPB(4, 0, 0, false,  xbR + 3200, P1, S1, P2, S2);
        STEPB(5, 0, 0, false,  xbR + 3840, P2, S2, P1, S1);
        STEPB(6, 0, pg, false, xbR + 4480, P1, S1, P2, S2);
        STEPB(7, 0, 0, false,  xbO,        P2, S2, P1, S1);
        xp += 256;                                // next group's prefetch base
    }

    // ---- peeled j=512 (parity 0): garbage L0 step (bounded), L1-step 510 ----
    {
        short* xsW = xs0;   // unused (XST=0); scoped alias for macro expansion
        STEPB(0, 0, 0, false, xb0, P1, S1, P2, S2);
    }

    // ---- peeled j=513 (parity 1): finish L1-step 511; only q>=2 used ----
    {
        const bf16x8 a1 = *(const bf16x8*)(haB + oH1);
        const bf16x8 a2 = *(const bf16x8*)(haB + oH1 + 32);
        const bf16x8 a5 = *(const bf16x8*)(hcB + oH2);
        const bf16x8 a6 = *(const bf16x8*)(hcB + oH2 + 32);
        P2 = mfma16(a1, BP_1, P2); S2 = mfma16(a1, BS_1, S2);
        P2 = mfma16(a2, BP_2, P2); S2 = mfma16(a2, BS_2, S2);
        P2 = mfma16(a5, BP_5, P2); S2 = mfma16(a5, BS_5, S2);
        P2 = mfma16(a6, BP_6, P2); S2 = mfma16(a6, BS_6, S2);
        float fv0, fv1, fv2, fv3, do0, do1, do2, do3;
        if (!roleB) {
            {   const float eg = ex2(P2[0]), ei = ex2(-S2[0]);
                igW[0]   = (eg - 1.0f) * rcp_f((1.0f + ei) * (1.0f + eg)); }
            {   const float eg = ex2(P2[1]), ei = ex2(-S2[1]);
                igW[256] = (eg - 1.0f) * rcp_f((1.0f + ei) * (1.0f + eg)); }
            {   const float eg = ex2(P2[2]), ei = ex2(-S2[2]);
                igW[512] = (eg - 1.0f) * rcp_f((1.0f + ei) * (1.0f + eg)); }
            {   const float eg = ex2(P2[3]), ei = ex2(-S2[3]);
                igW[768] = (eg - 1.0f) * rcp_f((1.0f + ei) * (1.0f + eg)); }
        } else {
            fv0 = rcp_f(1.0f + ex2(-P2[0])); do0 = 1.0f + ex2(-S2[0]);
            fv1 = rcp_f(1.0f + ex2(-P2[1])); do1 = 1.0f + ex2(-S2[1]);
            fv2 = rcp_f(1.0f + ex2(-P2[2])); do2 = 1.0f + ex2(-S2[2]);
            fv3 = rcp_f(1.0f + ex2(-P2[3])); do3 = 1.0f + ex2(-S2[3]);
        }
        asm volatile("s_waitcnt lgkmcnt(0)" ::: "memory");
        __builtin_amdgcn_s_barrier();
        if (roleB) {
            const float ig0 = igR[0],   ig1 = igR[256];
            const float ig2 = igR[512], ig3 = igR[768];
            float hv0, hv1, hv2, hv3;
            {   c0 = fmaf(fv0, c0, ig0); const float ec = ex2(c0 * L2E2);
                hv0 = (ec - 1.0f) * rcp_f(do0 * (1.0f + ec)); }
            {   c1 = fmaf(fv1, c1, ig1); const float ec = ex2(c1 * L2E2);
                hv1 = (ec - 1.0f) * rcp_f(do1 * (1.0f + ec)); }
            {   c2 = fmaf(fv2, c2, ig2); const float ec = ex2(c2 * L2E2);
                hv2 = (ec - 1.0f) * rcp_f(do2 * (1.0f + ec)); }
            {   c3 = fmaf(fv3, c3, ig3); const float ec = ex2(c3 * L2E2);
                hv3 = (ec - 1.0f) * rcp_f(do3 * (1.0f + ec)); }
            if (qhi) {                              // final h1 (step 511), fp32
                const int rl = (q & 1) * 4;
                HF[rl + 0][cell] = hv0;
                HF[rl + 1][cell] = hv1;
                HF[rl + 2][cell] = hv2;
                HF[rl + 3][cell] = hv3;
            }
        }
    }
    __syncthreads();

    // ---- epilogue: LayerNorm + FC; each of 8 waves handles 1 row ----
    const float lg = ln_g[lane], lb = ln_b[lane], fw = fcw[lane], fb = fcb[0];
    const float v = HF[wl][lane];
    float s1r = v, sqr = v * v;
#pragma unroll
    for (int mm = 1; mm < 64; mm <<= 1) {
        s1r += __shfl_xor(s1r, mm, 64);
        sqr += __shfl_xor(sqr, mm, 64);
    }
    const float mu = s1r * (1.0f / 64.0f);
    float var = sqr * (1.0f / 64.0f) - mu * mu;
    var = fmaxf(var, 0.0f);
    const float rs = rsqrtf(var + 1e-5f);
    float pv = ((v - mu) * rs * lg + lb) * fw;
#pragma unroll
    for (int mm = 1; mm < 64; mm <<= 1) pv += __shfl_xor(pv, mm, 64);
    if (lane == 0) out[rb + wl] = pv + fb;
}

extern "C" void kernel_launch(void* const* d_in, const int* in_sizes, int n_in,
                              void* d_out, int out_size, void* d_ws, size_t ws_size,
                              hipStream_t stream) {
    const float* x    = (const float*)d_in[0];
    const float* Wih0 = (const float*)d_in[1];
    const float* Whh0 = (const float*)d_in[2];
    const float* bih0 = (const float*)d_in[3];
    const float* bhh0 = (const float*)d_in[4];
    const float* Wih1 = (const float*)d_in[5];
    const float* Whh1 = (const float*)d_in[6];
    const float* bih1 = (const float*)d_in[7];
    const float* bhh1 = (const float*)d_in[8];
    const float* ln_g = (const float*)d_in[9];
    const float* ln_b = (const float*)d_in[10];
    const float* fcw  = (const float*)d_in[11];
    const float* fcb  = (const float*)d_in[12];

    dim3 grid(2048 / RPB);    // 256 blocks -> 1 per CU
    dim3 block(512);          // 8 waves: IG (0-3) + FO (4-7), 2/SIMD
    hipLaunchKernelGGL(lstm_mfma_68547678044465, grid, block, 0, stream,
                       x, Wih0, Whh0, bih0, bhh0, Wih1, Whh1, bih1, bhh1,
                       ln_g, ln_b, fcw, fcb, (float*)d_out);
}

// Round 11
// 441.623 us; speedup vs baseline: 1.0593x; 1.0593x over previous
//
#include <hip/hip_runtime.h>
#include <math.h>

#define TSTEPS 512
#define RPB 8
#define L2E  1.4426950408889634f
#define L2E2 2.8853900817779268f   // 2*log2(e)

typedef __attribute__((ext_vector_type(4))) short short4v;
typedef __attribute__((ext_vector_type(8))) short short8;
typedef __attribute__((ext_vector_type(4))) float f32x4;
typedef __bf16 bf16x8 __attribute__((ext_vector_type(8)));

__device__ __forceinline__ short f2bf(float f) {            // RNE float->bf16
    union { float f; unsigned u; } v; v.f = f;
    return (short)((v.u + 0x7FFFu + ((v.u >> 16) & 1u)) >> 16);
}
__device__ __forceinline__ unsigned pkbf(float lo, float hi) {  // HW RNE pack
    unsigned r;
    asm("v_cvt_pk_bf16_f32 %0, %1, %2" : "=v"(r) : "v"(lo), "v"(hi));
    return r;
}
__device__ __forceinline__ float rcp_f(float x) { return __builtin_amdgcn_rcpf(x); }
__device__ __forceinline__ float ex2(float x)   { return __builtin_amdgcn_exp2f(x); }
__device__ __forceinline__ f32x4 mfma16(bf16x8 a, bf16x8 b, f32x4 c) {
    return __builtin_amdgcn_mfma_f32_16x16x32_bf16(a, b, c, 0, 0, 0);
}

// 256 blocks x 256 threads (4 waves, 1/SIMD). Merged 16x16 MFMA tile,
// K=224 block-diagonal, LAG-2 pipeline (r8), shared-rcp acts (r9).
// THIS ROUND (r10 gate-split rolled back: +2x bank conflicts, 2 barriers,
// serial phase-2 tail): capture MFMA||VALU overlap WITHIN the single wave
// via emitted instruction order (in-order issue: MFMA issue is ~1 slot,
// matrix pipe grinds in background; VALU between MFMAs dual-pipes):
//  * a0r REGISTER CARRY: x-frag for step t+1 loaded at END of step t
//    (x-stage moved to sub 4, so the group-boundary reload is 2 barriers
//    after the staging write -> race-free). The 4 Y-chunk0 MFMAs issue at
//    barrier-exit with NO lgkm wait, covering the h ds_read latency.
//  * ACT||Y-MFMA INTERLEAVE pinned by sched_barrier(0): {act row r;
//    2 Y-MFMAs} x4 units, register-only region (no waitcnt hazard). The 8
//    chunk-3/4 MFMAs grind under the ~600-cyc act stream instead of
//    extending the MFMA cluster.
// Per-acc accumulation order unchanged (X: 1,2,5,6; Y: 0,3,4) ->
// BIT-IDENTICAL output vs r9.
#define SBAR0 __builtin_amdgcn_sched_barrier(0)

#define STEPB(SUB, PREF, XST, FRZ, XRLD, XG, XI, XF, XO, YG, YI, YF, YO) do { \
    const short* haS_ = ((SUB) & 1) ? haB : haA;                        \
    const short* hcS_ = ((SUB) & 1) ? hcB : hcA;                        \
    const bf16x8 a1 = *(const bf16x8*)(haS_ + oH1);                     \
    const bf16x8 a2 = *(const bf16x8*)(haS_ + oH1 + 32);                \
    const bf16x8 a5 = *(const bf16x8*)(hcS_ + oH2);                     \
    const bf16x8 a6 = *(const bf16x8*)(hcS_ + oH2 + 32);                \
    const bf16x8 a3 = *(const bf16x8*)(haS_ + oH2);                     \
    const bf16x8 a4 = *(const bf16x8*)(haS_ + oH2 + 32);                \
    if (PREF) {                                                         \
        xr0 = *(const float4*)(xp);                                     \
        xr1 = *(const float4*)(xp + 16);                                \
    }                                                                   \
    /* Y chunk0 from CARRIED register: issues with no lgkm wait */      \
    YG = mfma16(a0r, B2_0, BG); YI = mfma16(a0r, B0_0, BI);             \
    YF = mfma16(a0r, B1_0, BF); YO = mfma16(a0r, B3_0, BO);             \
    /* cur-acc fresh chunks 1,2,5,6: 16 MFMAs, 4-way interleaved */     \
    XG = mfma16(a1, B2_1, XG); XI = mfma16(a1, B0_1, XI);               \
    XF = mfma16(a1, B1_1, XF); XO = mfma16(a1, B3_1, XO);               \
    XG = mfma16(a2, B2_2, XG); XI = mfma16(a2, B0_2, XI);               \
    XF = mfma16(a2, B1_2, XF); XO = mfma16(a2, B3_2, XO);               \
    XG = mfma16(a5, B2_5, XG); XI = mfma16(a5, B0_5, XI);               \
    XF = mfma16(a5, B1_5, XF); XO = mfma16(a5, B3_5, XO);               \
    XG = mfma16(a6, B2_6, XG); XI = mfma16(a6, B0_6, XI);               \
    XF = mfma16(a6, B1_6, XF); XO = mfma16(a6, B3_6, XO);               \
    SBAR0;                                                              \
    /* interleave units: act row r + 2 Y-MFMAs, pinned by SBAR0 */      \
    float hv0, hv1, hv2, hv3;                                           \
    {                                                                   \
        const float ei = ex2(-XI[0]), eg = ex2(XG[0]);                  \
        const float ig = (eg - 1.0f) * rcp_f((1.0f + ei) * (1.0f + eg)); \
        const float fv = rcp_f(1.0f + ex2(-XF[0]));                     \
        const float cn = fmaf(fv, c0, ig);                              \
        c0 = (FRZ) ? 0.0f : cn;                                         \
        const float eo = ex2(-XO[0]), ec = ex2(c0 * L2E2);              \
        hv0 = (ec - 1.0f) * rcp_f((1.0f + eo) * (1.0f + ec));           \
    }                                                                   \
    YG = mfma16(a3, B2_3, YG); YI = mfma16(a3, B0_3, YI);               \
    SBAR0;                                                              \
    {                                                                   \
        const float ei = ex2(-XI[1]), eg = ex2(XG[1]);                  \
        const float ig = (eg - 1.0f) * rcp_f((1.0f + ei) * (1.0f + eg)); \
        const float fv = rcp_f(1.0f + ex2(-XF[1]));                     \
        const float cn = fmaf(fv, c1, ig);                              \
        c1 = (FRZ) ? 0.0f : cn;                                         \
        const float eo = ex2(-XO[1]), ec = ex2(c1 * L2E2);              \
        hv1 = (ec - 1.0f) * rcp_f((1.0f + eo) * (1.0f + ec));           \
    }                                                                   \
    YF = mfma16(a3, B1_3, YF); YO = mfma16(a3, B3_3, YO);               \
    SBAR0;                                                              \
    {                                                                   \
        const float ei = ex2(-XI[2]), eg = ex2(XG[2]);                  \
        const float ig = (eg - 1.0f) * rcp_f((1.0f + ei) * (1.0f + eg)); \
        const float fv = rcp_f(1.0f + ex2(-XF[2]));                     \
        const float cn = fmaf(fv, c2, ig);                              \
        c2 = (FRZ) ? 0.0f : cn;                                         \
        const float eo = ex2(-XO[2]), ec = ex2(c2 * L2E2);              \
        hv2 = (ec - 1.0f) * rcp_f((1.0f + eo) * (1.0f + ec));           \
    }                                                                   \
    YG = mfma16(a4, B2_4, YG); YI = mfma16(a4, B0_4, YI);               \
    SBAR0;                                                              \
    {                                                                   \
        const float ei = ex2(-XI[3]), eg = ex2(XG[3]);                  \
        const float ig = (eg - 1.0f) * rcp_f((1.0f + ei) * (1.0f + eg)); \
        const float fv = rcp_f(1.0f + ex2(-XF[3]));                     \
        const float cn = fmaf(fv, c3, ig);                              \
        c3 = (FRZ) ? 0.0f : cn;                                         \
        const float eo = ex2(-XO[3]), ec = ex2(c3 * L2E2);              \
        hv3 = (ec - 1.0f) * rcp_f((1.0f + eo) * (1.0f + ec));           \
    }                                                                   \
    YF = mfma16(a4, B1_4, YF); YO = mfma16(a4, B3_4, YO);               \
    SBAR0;                                                              \
    short* hd_ = (((SUB) & 1) == 0) ? hw1 : hw0;                        \
    const unsigned pA_ = pkbf(hv0, hv1);                                \
    const unsigned pB_ = pkbf(hv2, hv3);                                \
    hd_[0]   = (short)pA_; hd_[72]  = (short)(pA_ >> 16);               \
    hd_[144] = (short)pB_; hd_[216] = (short)(pB_ >> 16);               \
    if (XST) {                                                          \
        short4v pa_; pa_[0] = f2bf(xr0.x); pa_[1] = f2bf(xr0.y);        \
        pa_[2] = f2bf(xr0.z); pa_[3] = f2bf(xr0.w);                     \
        *(short4v*)(xsW) = pa_;                                         \
        short4v pb_; pb_[0] = f2bf(xr1.x); pb_[1] = f2bf(xr1.y);        \
        pb_[2] = f2bf(xr1.z); pb_[3] = f2bf(xr1.w);                     \
        *(short4v*)(xsW + 16) = pb_;                                    \
    }                                                                   \
    a0r = *(const bf16x8*)(XRLD);   /* x frag for step t+2 (stable buf) */ \
    asm volatile("s_waitcnt lgkmcnt(0)" ::: "memory");                  \
    __builtin_amdgcn_s_barrier();                                       \
} while (0)

__global__ __launch_bounds__(256)
void lstm_mfma_68547678044465(const float* __restrict__ x,
                              const float* __restrict__ Wih0, const float* __restrict__ Whh0,
                              const float* __restrict__ bih0, const float* __restrict__ bhh0,
                              const float* __restrict__ Wih1, const float* __restrict__ Whh1,
                              const float* __restrict__ bih1, const float* __restrict__ bhh1,
                              const float* __restrict__ ln_g, const float* __restrict__ ln_b,
                              const float* __restrict__ fcw, const float* __restrict__ fcb,
                              float* __restrict__ out)
{
    __shared__ __align__(16) short XB[2][8][16][40];  // x bf16; rows 8-15 always zero
    __shared__ __align__(16) short HA[2][24][72];     // rows 0-7 zero | 8-15 h0 | 16-23 zero
    __shared__ __align__(16) short HC[2][16][72];     // rows 0-7 zero | 8-15 h1
    __shared__ __align__(16) float HF[8][64];         // final h1 fp32 for LN

    const int tid  = threadIdx.x;
    const int wl   = tid >> 6;           // wave 0..3
    const int lane = tid & 63;
    const int n    = lane & 15;          // A row m / C col n
    const int q    = lane >> 4;          // k-quad / C row group
    const int rb   = blockIdx.x * RPB;
    const int cell = wl * 16 + n;        // h-dim cell 0..63
    const bool qhi = (q >= 2);

    // ---- B-fragments: 4 gate-tiles x 7 K-chunks, named registers ----
    auto loadB = [&](const float* wrow, float sc) -> bf16x8 {
        const float4 lo = *(const float4*)(wrow);
        const float4 hi = *(const float4*)(wrow + 4);
        short8 r;
        r[0] = f2bf(lo.x * sc); r[1] = f2bf(lo.y * sc);
        r[2] = f2bf(lo.z * sc); r[3] = f2bf(lo.w * sc);
        r[4] = f2bf(hi.x * sc); r[5] = f2bf(hi.y * sc);
        r[6] = f2bf(hi.z * sc); r[7] = f2bf(hi.w * sc);
        return (bf16x8)r;
    };
    const int g0 = cell, g1 = 64 + cell, g2 = 128 + cell, g3 = 192 + cell;
    const int ko = q * 8;
    const bf16x8 B0_0 = loadB(Wih0 + g0 * 32 + ko, L2E);
    const bf16x8 B0_1 = loadB(Whh0 + g0 * 64 + ko, L2E);
    const bf16x8 B0_2 = loadB(Whh0 + g0 * 64 + 32 + ko, L2E);
    const bf16x8 B0_3 = loadB(Wih1 + g0 * 64 + ko, L2E);
    const bf16x8 B0_4 = loadB(Wih1 + g0 * 64 + 32 + ko, L2E);
    const bf16x8 B0_5 = loadB(Whh1 + g0 * 64 + ko, L2E);
    const bf16x8 B0_6 = loadB(Whh1 + g0 * 64 + 32 + ko, L2E);
    const bf16x8 B1_0 = loadB(Wih0 + g1 * 32 + ko, L2E);
    const bf16x8 B1_1 = loadB(Whh0 + g1 * 64 + ko, L2E);
    const bf16x8 B1_2 = loadB(Whh0 + g1 * 64 + 32 + ko, L2E);
    const bf16x8 B1_3 = loadB(Wih1 + g1 * 64 + ko, L2E);
    const bf16x8 B1_4 = loadB(Wih1 + g1 * 64 + 32 + ko, L2E);
    const bf16x8 B1_5 = loadB(Whh1 + g1 * 64 + ko, L2E);
    const bf16x8 B1_6 = loadB(Whh1 + g1 * 64 + 32 + ko, L2E);
    const bf16x8 B2_0 = loadB(Wih0 + g2 * 32 + ko, L2E2);
    const bf16x8 B2_1 = loadB(Whh0 + g2 * 64 + ko, L2E2);
    const bf16x8 B2_2 = loadB(Whh0 + g2 * 64 + 32 + ko, L2E2);
    const bf16x8 B2_3 = loadB(Wih1 + g2 * 64 + ko, L2E2);
    const bf16x8 B2_4 = loadB(Wih1 + g2 * 64 + 32 + ko, L2E2);
    const bf16x8 B2_5 = loadB(Whh1 + g2 * 64 + ko, L2E2);
    const bf16x8 B2_6 = loadB(Whh1 + g2 * 64 + 32 + ko, L2E2);
    const bf16x8 B3_0 = loadB(Wih0 + g3 * 32 + ko, L2E);
    const bf16x8 B3_1 = loadB(Whh0 + g3 * 64 + ko, L2E);
    const bf16x8 B3_2 = loadB(Whh0 + g3 * 64 + 32 + ko, L2E);
    const bf16x8 B3_3 = loadB(Wih1 + g3 * 64 + ko, L2E);
    const bf16x8 B3_4 = loadB(Wih1 + g3 * 64 + 32 + ko, L2E);
    const bf16x8 B3_5 = loadB(Whh1 + g3 * 64 + ko, L2E);
    const bf16x8 B3_6 = loadB(Whh1 + g3 * 64 + 32 + ko, L2E);

    // ---- biases: per-lane layer select (q<2 -> L0 rows, q>=2 -> L1 rows) ----
    float b0, b1, b2, b3;
    if (!qhi) {
        b0 = (bih0[g0] + bhh0[g0]) * L2E;  b1 = (bih0[g1] + bhh0[g1]) * L2E;
        b2 = (bih0[g2] + bhh0[g2]) * L2E2; b3 = (bih0[g3] + bhh0[g3]) * L2E;
    } else {
        b0 = (bih1[g0] + bhh1[g0]) * L2E;  b1 = (bih1[g1] + bhh1[g1]) * L2E;
        b2 = (bih1[g2] + bhh1[g2]) * L2E2; b3 = (bih1[g3] + bhh1[g3]) * L2E;
    }
    const f32x4 BI = {b0, b0, b0, b0}, BF = {b1, b1, b1, b1},
                BG = {b2, b2, b2, b2}, BO = {b3, b3, b3, b3};

    // ---- zero all LDS (zero rows must stay zero; parity bufs start 0) ----
    { int* z = (int*)XB; for (int i = tid; i < 5120; i += 256) z[i] = 0; }
    { int* z = (int*)HA; for (int i = tid; i < 1728; i += 256) z[i] = 0; }
    { int* z = (int*)HC; for (int i = tid; i < 1152; i += 256) z[i] = 0; }

    // ---- per-lane invariant LDS pointers / offsets ----
    const short* haA = &HA[0][0][0];
    const short* haB = &HA[1][0][0];
    const short* hcA = &HC[0][0][0];
    const short* hcB = &HC[1][0][0];
    const int oH1 = (8 + n) * 72 + q * 8;     // h0 rows 8+m (L0 side)
    const int oH2 = n * 72 + q * 8;           // rows m (zero pad | data)
    const short* xb0 = &XB[0][0][0][0] + (n * 40 + q * 8);
    const short* xb1 = xb0 + 5120;
    short* hw0 = (qhi ? &HC[0][8 + (q & 1) * 4][0]
                      : &HA[0][8 + (q & 1) * 4][0]) + cell;   // parity-0 target
    short* hw1 = (qhi ? &HC[1][8 + (q & 1) * 4][0]
                      : &HA[1][8 + (q & 1) * 4][0]) + cell;   // parity-1 target

    // ---- x staging: thread -> (step ss, row sm, quad kq), 2 float4 each ----
    const int ss = tid >> 5, sm = (tid >> 2) & 7, kq = tid & 3;
    const float* xrow = x + (size_t)(rb + sm) * (TSTEPS * 32);
    short* xs0 = &XB[0][ss][sm][0] + kq * 4;
    short* xs1 = xs0 + 5120;
    const float* xp = xrow + (8 + ss) * 32 + kq * 4;   // group-1 prefetch base
    float4 xr0 = *(const float4*)(xrow + ss * 32 + kq * 4);
    float4 xr1 = *(const float4*)(xrow + ss * 32 + kq * 4 + 16);
    {   // initial stage of group 0 into buf 0
        short4v pa; pa[0] = f2bf(xr0.x); pa[1] = f2bf(xr0.y);
        pa[2] = f2bf(xr0.z); pa[3] = f2bf(xr0.w);
        *(short4v*)(xs0) = pa;
        short4v pb; pb[0] = f2bf(xr1.x); pb[1] = f2bf(xr1.y);
        pb[2] = f2bf(xr1.z); pb[3] = f2bf(xr1.w);
        *(short4v*)(xs0 + 16) = pb;
    }
    __syncthreads();

    float c0 = 0.0f, c1 = 0.0f, c2 = 0.0f, c3 = 0.0f;

    // ---- prologue: cur-accs for j=0 = bias + x_0 chunk 0; carry x_1 ----
    f32x4 AG1, AI1, AF1, AO1;
    f32x4 AG2 = {0, 0, 0, 0}, AI2 = {0, 0, 0, 0},
          AF2 = {0, 0, 0, 0}, AO2 = {0, 0, 0, 0};
    bf16x8 a0r;
    {
        const bf16x8 a0p = *(const bf16x8*)(xb0);      // x_0 frag
        AG1 = mfma16(a0p, B2_0, BG); AI1 = mfma16(a0p, B0_0, BI);
        AF1 = mfma16(a0p, B1_0, BF); AO1 = mfma16(a0p, B3_0, BO);
        a0r = *(const bf16x8*)(xb0 + 640);             // x_1 for iter-0's Y
    }

#pragma unroll 1
    for (int g = 0; g < 64; ++g) {
        const short* xbR = (g & 1) ? xb1 : xb0;   // read buf = g&1
        const short* xbO = (g & 1) ? xb0 : xb1;   // other buf (next group)
        short* xsW       = (g & 1) ? xs0 : xs1;   // stage target = (g+1)&1
        const bool fz = (g == 0) && qhi;          // phantom L1 steps -2,-1
        const bool pg = (g < 63);
        STEPB(0, pg, 0, fz,    xbR + 1280, AG1, AI1, AF1, AO1, AG2, AI2, AF2, AO2);
        STEPB(1, 0, 0, fz,     xbR + 1920, AG2, AI2, AF2, AO2, AG1, AI1, AF1, AO1);
        STEPB(2, 0, 0, false,  xbR + 2560, AG1, AI1, AF1, AO1, AG2, AI2, AF2, AO2);
        STEPB(3, 0, 0, false,  xbR + 3200, AG2, AI2, AF2, AO2, AG1, AI1, AF1, AO1);
        STEPB(4, 0, pg, false, xbR + 3840, AG1, AI1, AF1, AO1, AG2, AI2, AF2, AO2);
        STEPB(5, 0, 0, false,  xbR + 4480, AG2, AI2, AF2, AO2, AG1, AI1, AF1, AO1);
        STEPB(6, 0, 0, false,  xbO,        AG1, AI1, AF1, AO1, AG2, AI2, AF2, AO2);
        STEPB(7, 0, 0, false,  xbO + 640,  AG2, AI2, AF2, AO2, AG1, AI1, AF1, AO1);
        xp += 256;                                // next group's prefetch base
    }

    // ---- peeled j=512 (parity 0): L0 garbage step (bounded), L1-step 510.
    // Next-accs get stale-x garbage (L0 rows only) + h0^{511} (L1 rows).
    {
        short* xsW = xs0;   // unused (XST=0); scoped alias for macro expansion
        STEPB(0, 0, 0, false, xb0, AG1, AI1, AF1, AO1, AG2, AI2, AF2, AO2);
    }

    // ---- peeled j=513 (parity 1): finish L1-step 511; only q>=2 used ----
    {
        const bf16x8 a1 = *(const bf16x8*)(haB + oH1);
        const bf16x8 a2 = *(const bf16x8*)(haB + oH1 + 32);
        const bf16x8 a5 = *(const bf16x8*)(hcB + oH2);
        const bf16x8 a6 = *(const bf16x8*)(hcB + oH2 + 32);
        AG2 = mfma16(a1, B2_1, AG2); AI2 = mfma16(a1, B0_1, AI2);
        AF2 = mfma16(a1, B1_1, AF2); AO2 = mfma16(a1, B3_1, AO2);
        AG2 = mfma16(a2, B2_2, AG2); AI2 = mfma16(a2, B0_2, AI2);
        AF2 = mfma16(a2, B1_2, AF2); AO2 = mfma16(a2, B3_2, AO2);
        AG2 = mfma16(a5, B2_5, AG2); AI2 = mfma16(a5, B0_5, AI2);
        AF2 = mfma16(a5, B1_5, AF2); AO2 = mfma16(a5, B3_5, AO2);
        AG2 = mfma16(a6, B2_6, AG2); AI2 = mfma16(a6, B0_6, AI2);
        AF2 = mfma16(a6, B1_6, AF2); AO2 = mfma16(a6, B3_6, AO2);
        float hv0, hv1, hv2, hv3;
        {
            const float ei = ex2(-AI2[0]), eg = ex2(AG2[0]);
            const float ig = (eg - 1.0f) * rcp_f((1.0f + ei) * (1.0f + eg));
            const float fv = rcp_f(1.0f + ex2(-AF2[0]));
            c0 = fmaf(fv, c0, ig);
            const float eo = ex2(-AO2[0]), ec = ex2(c0 * L2E2);
            hv0 = (ec - 1.0f) * rcp_f((1.0f + eo) * (1.0f + ec));
        }
        {
            const float ei = ex2(-AI2[1]), eg = ex2(AG2[1]);
            const float ig = (eg - 1.0f) * rcp_f((1.0f + ei) * (1.0f + eg));
            const float fv = rcp_f(1.0f + ex2(-AF2[1]));
            c1 = fmaf(fv, c1, ig);
            const float eo = ex2(-AO2[1]), ec = ex2(c1 * L2E2);
            hv1 = (ec - 1.0f) * rcp_f((1.0f + eo) * (1.0f + ec));
        }
        {
            const float ei = ex2(-AI2[2]), eg = ex2(AG2[2]);
            const float ig = (eg - 1.0f) * rcp_f((1.0f + ei) * (1.0f + eg));
            const float fv = rcp_f(1.0f + ex2(-AF2[2]));
            c2 = fmaf(fv, c2, ig);
            const float eo = ex2(-AO2[2]), ec = ex2(c2 * L2E2);
            hv2 = (ec - 1.0f) * rcp_f((1.0f + eo) * (1.0f + ec));
        }
        {
            const float ei = ex2(-AI2[3]), eg = ex2(AG2[3]);
            const float ig = (eg - 1.0f) * rcp_f((1.0f + ei) * (1.0f + eg));
            const float fv = rcp_f(1.0f + ex2(-AF2[3]));
            c3 = fmaf(fv, c3, ig);
            const float eo = ex2(-AO2[3]), ec = ex2(c3 * L2E2);
            hv3 = (ec - 1.0f) * rcp_f((1.0f + eo) * (1.0f + ec));
        }
        if (qhi) {                              // final h1 (step 511), fp32
            const int rl = (q & 1) * 4;
            HF[rl + 0][cell] = hv0;
            HF[rl + 1][cell] = hv1;
            HF[rl + 2][cell] = hv2;
            HF[rl + 3][cell] = hv3;
        }
    }
    __syncthreads();

    // ---- epilogue: LayerNorm + FC; each wave handles 2 rows ----
    const float lg = ln_g[lane], lb = ln_b[lane], fw = fcw[lane], fb = fcb[0];
#pragma unroll
    for (int rr = 0; rr < 2; ++rr) {
        const int row = wl * 2 + rr;
        const float v = HF[row][lane];
        float s1 = v, sq = v * v;
#pragma unroll
        for (int mm = 1; mm < 64; mm <<= 1) {
            s1 += __shfl_xor(s1, mm, 64);
            sq += __shfl_xor(sq, mm, 64);
        }
        const float mu = s1 * (1.0f / 64.0f);
        float var = sq * (1.0f / 64.0f) - mu * mu;
        var = fmaxf(var, 0.0f);
        const float rs = rsqrtf(var + 1e-5f);
        float pv = ((v - mu) * rs * lg + lb) * fw;
#pragma unroll
        for (int mm = 1; mm < 64; mm <<= 1) pv += __shfl_xor(pv, mm, 64);
        if (lane == 0) out[rb + row] = pv + fb;
    }
}

extern "C" void kernel_launch(void* const* d_in, const int* in_sizes, int n_in,
                              void* d_out, int out_size, void* d_ws, size_t ws_size,
                              hipStream_t stream) {
    const float* x    = (const float*)d_in[0];
    const float* Wih0 = (const float*)d_in[1];
    const float* Whh0 = (const float*)d_in[2];
    const float* bih0 = (const float*)d_in[3];
    const float* bhh0 = (const float*)d_in[4];
    const float* Wih1 = (const float*)d_in[5];
    const float* Whh1 = (const float*)d_in[6];
    const float* bih1 = (const float*)d_in[7];
    const float* bhh1 = (const float*)d_in[8];
    const float* ln_g = (const float*)d_in[9];
    const float* ln_b = (const float*)d_in[10];
    const float* fcw  = (const float*)d_in[11];
    const float* fcb  = (const float*)d_in[12];

    dim3 grid(2048 / RPB);    // 256 blocks -> 1 per CU
    dim3 block(256);          // 4 waves: 1 per SIMD
    hipLaunchKernelGGL(lstm_mfma_68547678044465, grid, block, 0, stream,
                       x, Wih0, Whh0, bih0, bhh0, Wih1, Whh1, bih1, bhh1,
                       ln_g, ln_b, fcw, fcb, (float*)d_out);
}